// Round 1
// baseline (3050.895 us; speedup 1.0000x reference)
//
#include <hip/hip_runtime.h>

// ---------------------------------------------------------------------------
// Adaptive Computation Time GRU (B=32768, H=512, L=10), fp32 throughout.
// Strategy: active-row compaction. Rows that halt (cum -> exactly 1.0f) only
// contribute with weight 1e-15 afterwards (invisible at fp32); skip them.
// Per step:
//   k_halt : gathered GEMM  a1 = h@W1^T, fused relu * w2 row-reduction -> p partials
//   k_book : p = sigmoid(sum partials + b2); ACT bookkeeping; merged += h*p_step;
//            builds compacted survivor index list (deterministic results:
//            atomic order only permutes the list, never any summation order)
//   k_gru  : gathered GEMM over 6-interleaved gate weights; thread-local GRU
//            epilogue writes h_new (ping-pong buffer). emb contribution is a
//            precomputed per-layer bias vector (x@Wih = h@Wih + emb@Wih).
// ---------------------------------------------------------------------------

#define BM 128
#define BN 128   // halt col tile
#define BK 16
#define GBN 96   // gru col tile = 16 units * 6 gates

__global__ void k_init(float* __restrict__ cum, int* __restrict__ idxA,
                       int* __restrict__ counts, int B) {
    int i = blockIdx.x * blockDim.x + threadIdx.x;
    if (i < B) { cum[i] = 0.f; idxA[i] = i; }
    if (i == 0) { counts[0] = B; for (int l = 1; l < 16; ++l) counts[l] = 0; }
}

// Wg[(u*6+g)*H + k] : g in 0..2 -> w_ih[g*H+u], g in 3..5 -> w_hh[(g-3)*H+u]
__global__ void k_prep_wg(const float* __restrict__ w_ih, const float* __restrict__ w_hh,
                          float* __restrict__ Wg, int H) {
    long long total = (long long)6 * H * H;
    long long stride = (long long)gridDim.x * blockDim.x;
    for (long long i = (long long)blockIdx.x * blockDim.x + threadIdx.x; i < total; i += stride) {
        int k = (int)(i % H);
        int rowg = (int)(i / H);
        int g = rowg % 6;
        int u = rowg / 6;
        float v = (g < 3) ? w_ih[((long long)(g * H + u)) * H + k]
                          : w_hh[((long long)((g - 3) * H + u)) * H + k];
        Wg[i] = v;
    }
}

// cg[l][u*6+g] = (g<3) ? b_ih[g*H+u] + dot(emb[l], w_ih_row)  :  b_hh[(g-3)*H+u]
__global__ void k_prep_cg(const float* __restrict__ emb, const float* __restrict__ w_ih,
                          const float* __restrict__ b_ih, const float* __restrict__ b_hh,
                          float* __restrict__ cg, int H, int L) {
    int total = L * 6 * H;
    for (int i = blockIdx.x * blockDim.x + threadIdx.x; i < total;
         i += gridDim.x * blockDim.x) {
        int g = i % 6;
        int u = (i / 6) % H;
        int l = i / (6 * H);
        float v;
        if (g < 3) {
            const float* w = w_ih + (long long)(g * H + u) * H;
            const float* e = emb + (long long)l * H;
            float s = 0.f;
            #pragma unroll 8
            for (int k = 0; k < H; ++k) s = fmaf(e[k], w[k], s);
            v = s + b_ih[g * H + u];
        } else {
            v = b_hh[(g - 3) * H + u];
        }
        cg[i] = v;
    }
}

// ---------------- halting GEMM: p_part[pos*NCB+ct] ----------------
__global__ __launch_bounds__(256) void k_halt(
        const float* __restrict__ h, const int* __restrict__ idx,
        const int* __restrict__ counts, int lslot,
        const float* __restrict__ W1, const float* __restrict__ b1,
        const float* __restrict__ w2, float* __restrict__ p_part,
        int H, int NCB) {
    int n = counts[lslot];
    int rt = blockIdx.x, ct = blockIdx.y;
    if (rt * BM >= n) return;
    __shared__ float As[BK][BM];
    __shared__ float Bs[BK][BN];
    __shared__ float red[BM][16];
    __shared__ int rid[BM];
    int tid = threadIdx.x;
    if (tid < BM) {
        int pos = rt * BM + tid;
        rid[tid] = idx[min(pos, n - 1)];
    }
    __syncthreads();
    int tm = tid >> 4, tn = tid & 15;
    float acc[8][8];
    #pragma unroll
    for (int i = 0; i < 8; ++i)
        #pragma unroll
        for (int j = 0; j < 8; ++j) acc[i][j] = 0.f;

    for (int k0 = 0; k0 < H; k0 += BK) {
        #pragma unroll
        for (int q = 0; q < 2; ++q) {
            int f4 = tid + q * 256;          // 512 float4 of A tile
            int row = f4 >> 2, c4 = f4 & 3;
            const float4 v = *reinterpret_cast<const float4*>(
                &h[(long long)rid[row] * H + k0 + c4 * 4]);
            As[c4 * 4 + 0][row] = v.x; As[c4 * 4 + 1][row] = v.y;
            As[c4 * 4 + 2][row] = v.z; As[c4 * 4 + 3][row] = v.w;
        }
        #pragma unroll
        for (int q = 0; q < 2; ++q) {
            int f4 = tid + q * 256;          // 512 float4 of W1 tile
            int row = f4 >> 2, c4 = f4 & 3;
            const float4 v = *reinterpret_cast<const float4*>(
                &W1[(long long)(ct * BN + row) * H + k0 + c4 * 4]);
            Bs[c4 * 4 + 0][row] = v.x; Bs[c4 * 4 + 1][row] = v.y;
            Bs[c4 * 4 + 2][row] = v.z; Bs[c4 * 4 + 3][row] = v.w;
        }
        __syncthreads();
        #pragma unroll
        for (int k = 0; k < BK; ++k) {
            float a[8], b[8];
            *reinterpret_cast<float4*>(&a[0]) = *reinterpret_cast<const float4*>(&As[k][tm * 8]);
            *reinterpret_cast<float4*>(&a[4]) = *reinterpret_cast<const float4*>(&As[k][tm * 8 + 4]);
            *reinterpret_cast<float4*>(&b[0]) = *reinterpret_cast<const float4*>(&Bs[k][tn * 8]);
            *reinterpret_cast<float4*>(&b[4]) = *reinterpret_cast<const float4*>(&Bs[k][tn * 8 + 4]);
            #pragma unroll
            for (int i = 0; i < 8; ++i)
                #pragma unroll
                for (int j = 0; j < 8; ++j)
                    acc[i][j] = fmaf(a[i], b[j], acc[i][j]);
        }
        __syncthreads();
    }
    // relu(a1 + b1) * w2, partial row sums
    float s[8];
    #pragma unroll
    for (int i = 0; i < 8; ++i) {
        float t = 0.f;
        #pragma unroll
        for (int j = 0; j < 8; ++j) {
            int c = ct * BN + tn * 8 + j;
            float v = acc[i][j] + b1[c];
            v = v > 0.f ? v : 0.f;
            t = fmaf(v, w2[c], t);
        }
        s[i] = t;
    }
    #pragma unroll
    for (int i = 0; i < 8; ++i) red[tm * 8 + i][tn] = s[i];
    __syncthreads();
    if (tid < BM) {
        float t = 0.f;
        #pragma unroll
        for (int j = 0; j < 16; ++j) t += red[tid][j];
        int pos = rt * BM + tid;
        if (pos < n) p_part[(long long)pos * NCB + ct] = t;
    }
}

// ---------------- bookkeeping ----------------
__global__ void k_book(const float* __restrict__ p_part, const float* __restrict__ b2,
                       float* __restrict__ cum, const float* __restrict__ h,
                       const int* __restrict__ idx, const int* __restrict__ counts, int lslot,
                       float* __restrict__ out, int* __restrict__ idx_next,
                       int* __restrict__ count_next, int B, int H, int NCB, int first) {
    int n = counts[lslot];
    __shared__ float sh_pstep;
    __shared__ int sh_row;
    for (int pos = blockIdx.x; pos < n; pos += gridDim.x) {
        if (threadIdx.x == 0) {
            int row = idx[pos];
            float s = 0.f;
            for (int c = 0; c < NCB; ++c) s += p_part[(long long)pos * NCB + c];
            s += b2[0];
            float p = 1.f / (1.f + expf(-s));
            float cb = cum[row];
            bool halted = (p + cb > 0.9f);            // p*alive + cum > THRESHOLD, alive==1
            float rem = (1.f - cb) + 1e-15f;
            float p_step = halted ? rem : p;
            cum[row] = cb + p_step;
            long long BH = (long long)B * H;
            if (first) {
                out[BH + row]     = halted ? 0.f : p_step;   // accumulated_halting
                out[BH + B + row] = halted ? 0.f : 1.f;      // num_updated
            } else if (!halted) {
                out[BH + row]     += p_step;
                out[BH + B + row] += 1.f;
            }
            if (!halted) {
                int slot = atomicAdd(count_next, 1);
                idx_next[slot] = row;
            }
            sh_row = row;
            sh_pstep = p_step;
        }
        __syncthreads();
        int row = sh_row;
        float ps = sh_pstep;
        const float* hr = h + (long long)row * H;
        float* mr = out + (long long)row * H;
        if (first) {
            for (int j = threadIdx.x; j < H; j += blockDim.x) mr[j] = hr[j] * ps;
        } else {
            for (int j = threadIdx.x; j < H; j += blockDim.x) mr[j] = fmaf(hr[j], ps, mr[j]);
        }
        __syncthreads();
    }
}

// ---------------- GRU GEMM (interleaved gates), thread-local epilogue ----------------
__global__ __launch_bounds__(256) void k_gru(
        const float* __restrict__ h, const int* __restrict__ idx,
        const int* __restrict__ counts, int lslot,
        const float* __restrict__ Wg, const float* __restrict__ cgl,
        float* __restrict__ hn, int H) {
    int n = counts[lslot];
    int rt = blockIdx.x, ct = blockIdx.y;
    if (rt * BM >= n) return;
    __shared__ float As[BK][BM];
    __shared__ float Bs[BK][GBN];
    __shared__ int rid[BM];
    int tid = threadIdx.x;
    if (tid < BM) {
        int pos = rt * BM + tid;
        rid[tid] = idx[min(pos, n - 1)];
    }
    __syncthreads();
    int tm = tid >> 4, tn = tid & 15;
    float acc[8][6];
    #pragma unroll
    for (int i = 0; i < 8; ++i)
        #pragma unroll
        for (int j = 0; j < 6; ++j) acc[i][j] = 0.f;

    for (int k0 = 0; k0 < H; k0 += BK) {
        #pragma unroll
        for (int q = 0; q < 2; ++q) {
            int f4 = tid + q * 256;
            int row = f4 >> 2, c4 = f4 & 3;
            const float4 v = *reinterpret_cast<const float4*>(
                &h[(long long)rid[row] * H + k0 + c4 * 4]);
            As[c4 * 4 + 0][row] = v.x; As[c4 * 4 + 1][row] = v.y;
            As[c4 * 4 + 2][row] = v.z; As[c4 * 4 + 3][row] = v.w;
        }
        #pragma unroll
        for (int q = 0; q < 2; ++q) {
            int f4 = tid + q * 256;          // 384 float4 of Wg tile
            if (f4 < (GBN * BK) / 4) {
                int row = f4 >> 2, c4 = f4 & 3;
                const float4 v = *reinterpret_cast<const float4*>(
                    &Wg[(long long)(ct * GBN + row) * H + k0 + c4 * 4]);
                Bs[c4 * 4 + 0][row] = v.x; Bs[c4 * 4 + 1][row] = v.y;
                Bs[c4 * 4 + 2][row] = v.z; Bs[c4 * 4 + 3][row] = v.w;
            }
        }
        __syncthreads();
        #pragma unroll
        for (int k = 0; k < BK; ++k) {
            float a[8], b[6];
            *reinterpret_cast<float4*>(&a[0]) = *reinterpret_cast<const float4*>(&As[k][tm * 8]);
            *reinterpret_cast<float4*>(&a[4]) = *reinterpret_cast<const float4*>(&As[k][tm * 8 + 4]);
            *reinterpret_cast<float2*>(&b[0]) = *reinterpret_cast<const float2*>(&Bs[k][tn * 6]);
            *reinterpret_cast<float2*>(&b[2]) = *reinterpret_cast<const float2*>(&Bs[k][tn * 6 + 2]);
            *reinterpret_cast<float2*>(&b[4]) = *reinterpret_cast<const float2*>(&Bs[k][tn * 6 + 4]);
            #pragma unroll
            for (int i = 0; i < 8; ++i)
                #pragma unroll
                for (int j = 0; j < 6; ++j)
                    acc[i][j] = fmaf(a[i], b[j], acc[i][j]);
        }
        __syncthreads();
    }
    // epilogue: unit u = ct*16 + tn, gates [ih_r, ih_z, ih_n, hh_r, hh_z, hh_n]
    int u = ct * 16 + tn;
    float cgv[6];
    #pragma unroll
    for (int g = 0; g < 6; ++g) cgv[g] = cgl[u * 6 + g];
    #pragma unroll
    for (int i = 0; i < 8; ++i) {
        int pos = rt * BM + tm * 8 + i;
        if (pos < n) {
            int row = rid[tm * 8 + i];
            float ir = acc[i][0] + cgv[0], hr = acc[i][3] + cgv[3];
            float iz = acc[i][1] + cgv[1], hz = acc[i][4] + cgv[4];
            float in_ = acc[i][2] + cgv[2], hnv = acc[i][5] + cgv[5];
            float r = 1.f / (1.f + expf(-(ir + hr)));
            float z = 1.f / (1.f + expf(-(iz + hz)));
            float nn = tanhf(fmaf(r, hnv, in_));
            float ho = h[(long long)row * H + u];
            hn[(long long)row * H + u] = (1.f - z) * nn + z * ho;
        }
    }
}

extern "C" void kernel_launch(void* const* d_in, const int* in_sizes, int n_in,
                              void* d_out, int out_size, void* d_ws, size_t ws_size,
                              hipStream_t stream) {
    const float* hidden  = (const float*)d_in[1];
    const float* halt_w1 = (const float*)d_in[2];
    const float* halt_b1 = (const float*)d_in[3];
    const float* halt_w2 = (const float*)d_in[4];
    const float* halt_b2 = (const float*)d_in[5];
    const float* w_ih    = (const float*)d_in[6];
    const float* w_hh    = (const float*)d_in[7];
    const float* b_ih    = (const float*)d_in[8];
    const float* b_hh    = (const float*)d_in[9];
    const float* demb    = (const float*)d_in[10];

    const int H = in_sizes[3];          // 512
    const int B = in_sizes[1] / H;      // 32768
    const int L = in_sizes[10] / H;     // 10
    const int NCB = H / BN;             // 4

    float* out = (float*)d_out;

    // workspace carve (256B aligned)
    char* w = (char*)d_ws;
    auto alloc = [&](size_t bytes) {
        char* p = w;
        w += (bytes + 255) & ~(size_t)255;
        return p;
    };
    float* hA    = (float*)alloc((size_t)B * H * 4);
    float* hB    = (float*)alloc((size_t)B * H * 4);
    float* Wg    = (float*)alloc((size_t)6 * H * H * 4);
    float* cg    = (float*)alloc((size_t)L * 6 * H * 4);
    float* ppart = (float*)alloc((size_t)B * NCB * 4);
    float* cum   = (float*)alloc((size_t)B * 4);
    int* idxA    = (int*)alloc((size_t)B * 4);
    int* idxB    = (int*)alloc((size_t)B * 4);
    int* counts  = (int*)alloc(64);
    (void)ws_size; (void)n_in; (void)out_size;

    k_init<<<(B + 255) / 256, 256, 0, stream>>>(cum, idxA, counts, B);
    k_prep_wg<<<2048, 256, 0, stream>>>(w_ih, w_hh, Wg, H);
    k_prep_cg<<<(L * 6 * H + 255) / 256, 256, 0, stream>>>(demb, w_ih, b_ih, b_hh, cg, H, L);

    const float* hc = hidden;   // step 0 reads the input hidden state directly
    float* hnx = hA;
    float* hother = hB;
    int* ia = idxA;
    int* ib = idxB;

    dim3 hgrid((B + BM - 1) / BM, NCB);
    dim3 ggrid((B + BM - 1) / BM, (6 * H) / GBN);

    for (int l = 0; l < L; ++l) {
        k_halt<<<hgrid, 256, 0, stream>>>(hc, ia, counts, l, halt_w1, halt_b1,
                                          halt_w2, ppart, H, NCB);
        k_book<<<2048, 256, 0, stream>>>(ppart, halt_b2, cum, hc, ia, counts, l,
                                         out, ib, counts + (l + 1), B, H, NCB,
                                         l == 0 ? 1 : 0);
        if (l + 1 < L) {
            k_gru<<<ggrid, 256, 0, stream>>>(hc, ib, counts, l + 1, Wg,
                                             cg + (size_t)l * 6 * H, hnx, H);
            // ping-pong h buffers, swap index lists
            const float* read_next = hnx;
            hnx = (l == 0) ? hother : (float*)hc;
            hc = read_next;
            int* t = ia; ia = ib; ib = t;
        }
    }
}

// Round 3
// 1763.807 us; speedup vs baseline: 1.7297x; 1.7297x over previous
//
#include <hip/hip_runtime.h>

// ---------------------------------------------------------------------------
// ACT-GRU (B=32768, H=512, L=10) with bf16x3 MFMA GEMMs.
// Numerics: every fp32 operand x is split x = hi + lo (bf16 each, RTNE);
// products hi*hi + hi*lo + lo*hi on mfma_f32_16x16x32_bf16 (fp32 accum)
// give ~3*2^-18 per-term error. The halt logit passes through the H->1
// contraction (||w2|| ~ 0.3) so p-noise ~4e-7: threshold-flip risk ~0.1
// expected flips over 82k tests. h is stored ONLY as the (hi,lo) bf16 pair.
// Weights are pre-split into fragment-linear layout so each MFMA B-fragment
// is one coalesced 16B/lane global load (L2-resident). The gathered h tile
// is LDS-staged with an XOR chunk swizzle (conflict-free ds_read_b128).
// MFMA layouts (gfx950 16x16x32): A: row=l&15, k=(l>>4)*8+e ;
// B: col=l&15, k=(l>>4)*8+e ; C: col=l&15, row=(l>>4)*4+reg  [m89-verified].
// ---------------------------------------------------------------------------

typedef __attribute__((ext_vector_type(8))) short bf16x8;
typedef __attribute__((ext_vector_type(4))) float f32x4;

#define BM 128

__device__ __forceinline__ unsigned short f2bf(float x) {
    unsigned int u = __float_as_uint(x);
    u += 0x7fffu + ((u >> 16) & 1u);          // RTNE
    return (unsigned short)(u >> 16);
}
__device__ __forceinline__ float bf2f(unsigned short b) {
    return __uint_as_float(((unsigned int)b) << 16);
}
__device__ __forceinline__ int swz(int r, int kc) { return kc ^ ((r ^ (r >> 2)) & 3); }

__global__ void k_init(float* __restrict__ cum, int* __restrict__ idxA,
                       int* __restrict__ counts, int B) {
    int i = blockIdx.x * blockDim.x + threadIdx.x;
    if (i < B) { cum[i] = 0.f; idxA[i] = i; }
    if (i == 0) { counts[0] = B; for (int l = 1; l < 16; ++l) counts[l] = 0; }
}

// split fp32 -> (hi,lo) bf16 pair, 8 elems/thread
__global__ void k_split(const float* __restrict__ x, unsigned short* __restrict__ hi,
                        unsigned short* __restrict__ lo, int n8) {
    int i = blockIdx.x * blockDim.x + threadIdx.x;
    if (i >= n8) return;
    const float4 v0 = ((const float4*)x)[2 * i];
    const float4 v1 = ((const float4*)x)[2 * i + 1];
    float v[8] = {v0.x, v0.y, v0.z, v0.w, v1.x, v1.y, v1.z, v1.w};
    bf16x8 vh, vl;
    #pragma unroll
    for (int e = 0; e < 8; ++e) {
        unsigned short h = f2bf(v[e]);
        vh[e] = (short)h;
        vl[e] = (short)f2bf(v[e] - bf2f(h));
    }
    *(bf16x8*)&hi[(long long)i * 8] = vh;
    *(bf16x8*)&lo[(long long)i * 8] = vl;
}

// halt W1 -> fragment-linear split: idx = ((((ct*16+ks)*8+j)*64+l)*8+e)
// col = ct*128+j*16+(l&15), k = ks*32+(l>>4)*8+e, val = w1[col*512+k]
__global__ void k_prep_w1f(const float* __restrict__ w1, unsigned short* __restrict__ fhi,
                           unsigned short* __restrict__ flo) {
    int i = blockIdx.x * blockDim.x + threadIdx.x;
    if (i >= 4 * 16 * 8 * 64 * 8) return;
    int e = i & 7, l = (i >> 3) & 63, j = (i >> 9) & 7, ks = (i >> 12) & 15, ct = i >> 16;
    int col = ct * 128 + j * 16 + (l & 15);
    int k = ks * 32 + (l >> 4) * 8 + e;
    float v = w1[(long long)col * 512 + k];
    unsigned short h = f2bf(v);
    fhi[i] = h;
    flo[i] = f2bf(v - bf2f(h));
}

// GRU gate weights, gate-interleaved col c=u*6+g, fragment-linear split:
// idx = ((((ct*16+ks)*6+j)*64+l)*8+e), col = ct*96+j*16+(l&15)
__global__ void k_prep_wgf(const float* __restrict__ w_ih, const float* __restrict__ w_hh,
                           unsigned short* __restrict__ fhi, unsigned short* __restrict__ flo) {
    int i = blockIdx.x * blockDim.x + threadIdx.x;
    if (i >= 32 * 16 * 6 * 64 * 8) return;
    int e = i & 7, l = (i >> 3) & 63;
    int t = i >> 9;
    int j = t % 6;
    int ksct = t / 6;
    int ks = ksct & 15, ct = ksct >> 4;
    int col = ct * 96 + j * 16 + (l & 15);
    int u = col / 6, g = col % 6;
    int k = ks * 32 + (l >> 4) * 8 + e;
    float v = (g < 3) ? w_ih[((long long)(g * 512 + u)) * 512 + k]
                      : w_hh[((long long)((g - 3) * 512 + u)) * 512 + k];
    unsigned short h = f2bf(v);
    fhi[i] = h;
    flo[i] = f2bf(v - bf2f(h));
}

// cg[l][u*6+g] = (g<3) ? b_ih[g*512+u] + dot(emb[l], w_ih_row) : b_hh[(g-3)*512+u]
__global__ void k_prep_cg(const float* __restrict__ emb, const float* __restrict__ w_ih,
                          const float* __restrict__ b_ih, const float* __restrict__ b_hh,
                          float* __restrict__ cg, int L) {
    int total = L * 6 * 512;
    for (int i = blockIdx.x * blockDim.x + threadIdx.x; i < total;
         i += gridDim.x * blockDim.x) {
        int g = i % 6;
        int u = (i / 6) % 512;
        int l = i / (6 * 512);
        float v;
        if (g < 3) {
            const float* w = w_ih + (long long)(g * 512 + u) * 512;
            const float* e = emb + (long long)l * 512;
            float s = 0.f;
            #pragma unroll 8
            for (int k = 0; k < 512; ++k) s = fmaf(e[k], w[k], s);
            v = s + b_ih[g * 512 + u];
        } else {
            v = b_hh[(g - 3) * 512 + u];
        }
        cg[i] = v;
    }
}

// ---------------- halting GEMM (MFMA bf16x3): p_part[pos*4+ct] ----------------
__global__ __launch_bounds__(256) void k_halt(
        const unsigned short* __restrict__ hhi, const unsigned short* __restrict__ hlo,
        const int* __restrict__ idx, const int* __restrict__ counts, int lslot,
        const unsigned short* __restrict__ w1hi, const unsigned short* __restrict__ w1lo,
        const float* __restrict__ b1, const float* __restrict__ w2,
        float* __restrict__ p_part) {
    int n = counts[lslot];
    int rt = blockIdx.x, ct = blockIdx.y;
    if (rt * BM >= n) return;
    __shared__ unsigned short sA[2 * 4096];   // [split][128 rows][32 k] swizzled, 16KB
    __shared__ int rid[BM];
    int tid = threadIdx.x;
    if (tid < BM) rid[tid] = idx[min(rt * BM + tid, n - 1)];
    __syncthreads();
    int w = tid >> 6, l = tid & 63;
    f32x4 acc[2][8];
    #pragma unroll
    for (int a = 0; a < 2; ++a)
        #pragma unroll
        for (int j = 0; j < 8; ++j) acc[a][j] = (f32x4){0.f, 0.f, 0.f, 0.f};

    for (int ks = 0; ks < 16; ++ks) {
        int k0 = ks * 32;
        #pragma unroll
        for (int q = 0; q < 4; ++q) {
            int c = tid + q * 256;
            int s = c >> 9, r = (c >> 2) & 127, kc = c & 3;
            const unsigned short* src = (s ? hlo : hhi) + (long long)rid[r] * 512 + k0 + kc * 8;
            bf16x8 v = *(const bf16x8*)src;
            *(bf16x8*)&sA[s * 4096 + r * 32 + 8 * swz(r, kc)] = v;
        }
        __syncthreads();
        bf16x8 ahi[2], alo[2];
        #pragma unroll
        for (int a = 0; a < 2; ++a) {
            int r = w * 32 + a * 16 + (l & 15);
            int off = r * 32 + 8 * swz(r, l >> 4);
            ahi[a] = *(const bf16x8*)&sA[off];
            alo[a] = *(const bf16x8*)&sA[4096 + off];
        }
        #pragma unroll
        for (int j = 0; j < 8; ++j) {
            int fb = ((((ct * 16 + ks) * 8 + j) * 64) + l) * 8;
            bf16x8 bh = *(const bf16x8*)&w1hi[fb];
            bf16x8 bl = *(const bf16x8*)&w1lo[fb];
            #pragma unroll
            for (int a = 0; a < 2; ++a) {
                acc[a][j] = __builtin_amdgcn_mfma_f32_16x16x32_bf16(ahi[a], bh, acc[a][j], 0, 0, 0);
                acc[a][j] = __builtin_amdgcn_mfma_f32_16x16x32_bf16(alo[a], bh, acc[a][j], 0, 0, 0);
                acc[a][j] = __builtin_amdgcn_mfma_f32_16x16x32_bf16(ahi[a], bl, acc[a][j], 0, 0, 0);
            }
        }
        __syncthreads();
    }
    // epilogue: relu(acc + b1[c]) * w2[c], reduce over the 128 cols of this ct
    int q = l >> 4;
    float sums[2][4];
    #pragma unroll
    for (int a = 0; a < 2; ++a)
        #pragma unroll
        for (int r = 0; r < 4; ++r) sums[a][r] = 0.f;
    #pragma unroll
    for (int j = 0; j < 8; ++j) {
        int cb = ct * 128 + j * 16 + (l & 15);
        float bb = b1[cb], ww = w2[cb];
        #pragma unroll
        for (int a = 0; a < 2; ++a)
            #pragma unroll
            for (int r = 0; r < 4; ++r) {
                float v = acc[a][j][r] + bb;
                v = v > 0.f ? v : 0.f;
                sums[a][r] = fmaf(v, ww, sums[a][r]);
            }
    }
    #pragma unroll
    for (int m = 1; m < 16; m <<= 1)
        #pragma unroll
        for (int a = 0; a < 2; ++a)
            #pragma unroll
            for (int r = 0; r < 4; ++r) sums[a][r] += __shfl_xor(sums[a][r], m, 64);
    if ((l & 15) == 0) {
        #pragma unroll
        for (int a = 0; a < 2; ++a)
            #pragma unroll
            for (int r = 0; r < 4; ++r) {
                int pos = rt * BM + w * 32 + a * 16 + q * 4 + r;
                if (pos < n) p_part[(long long)pos * 4 + ct] = sums[a][r];
            }
    }
}

// ---------------- bookkeeping: one wave per row ----------------
__global__ void k_book(const float* __restrict__ p_part, const float* __restrict__ b2,
                       float* __restrict__ cum,
                       const unsigned short* __restrict__ hhi,
                       const unsigned short* __restrict__ hlo,
                       const int* __restrict__ idx, const int* __restrict__ counts, int lslot,
                       float* __restrict__ out, int* __restrict__ idx_next,
                       int* __restrict__ count_next, int B, int first) {
    int n = counts[lslot];
    int wv = (blockIdx.x * blockDim.x + threadIdx.x) >> 6;
    int lane = threadIdx.x & 63;
    int nw = (gridDim.x * blockDim.x) >> 6;
    for (int pos = wv; pos < n; pos += nw) {
        int row = idx[pos];
        float ps = 0.f;
        if (lane == 0) {
            float s = p_part[(long long)pos * 4 + 0] + p_part[(long long)pos * 4 + 1] +
                      p_part[(long long)pos * 4 + 2] + p_part[(long long)pos * 4 + 3] + b2[0];
            float p = 1.f / (1.f + expf(-s));
            float cb = cum[row];
            int halted = (p + cb > 0.9f);
            float rem = (1.f - cb) + 1e-15f;
            ps = halted ? rem : p;
            cum[row] = cb + ps;
            long long BH = (long long)B * 512;
            if (first) {
                out[BH + row]     = halted ? 0.f : ps;
                out[BH + B + row] = halted ? 0.f : 1.f;
            } else if (!halted) {
                out[BH + row]     += ps;
                out[BH + B + row] += 1.f;
            }
            if (!halted) idx_next[atomicAdd(count_next, 1)] = row;
        }
        ps = __shfl(ps, 0, 64);
        long long hb = (long long)row * 512 + lane * 8;
        bf16x8 vh = *(const bf16x8*)&hhi[hb];
        bf16x8 vl = *(const bf16x8*)&hlo[hb];
        float* mr = out + hb;
        float vals[8];
        #pragma unroll
        for (int e = 0; e < 8; ++e)
            vals[e] = bf2f((unsigned short)vh[e]) + bf2f((unsigned short)vl[e]);
        if (first) {
            #pragma unroll
            for (int e = 0; e < 8; ++e) mr[e] = vals[e] * ps;
        } else {
            #pragma unroll
            for (int e = 0; e < 8; ++e) mr[e] = fmaf(vals[e], ps, mr[e]);
        }
    }
}

// ---------------- GRU GEMM (MFMA bf16x3) + LDS-exchange epilogue ----------------
__global__ __launch_bounds__(256) void k_gru(
        const unsigned short* __restrict__ hhi, const unsigned short* __restrict__ hlo,
        const int* __restrict__ idx, const int* __restrict__ counts, int lslot,
        const unsigned short* __restrict__ wghi, const unsigned short* __restrict__ wglo,
        const float* __restrict__ cgl,
        unsigned short* __restrict__ nhi, unsigned short* __restrict__ nlo) {
    int n = counts[lslot];
    int rt = blockIdx.x, ct = blockIdx.y;
    if (rt * BM >= n) return;
    __shared__ unsigned int smem[12416];      // staging 16KB, then gate tile [128][97] f32
    __shared__ int rid[BM];
    unsigned short* sA = (unsigned short*)smem;
    float* gt = (float*)smem;
    int tid = threadIdx.x;
    if (tid < BM) rid[tid] = idx[min(rt * BM + tid, n - 1)];
    __syncthreads();
    int w = tid >> 6, l = tid & 63;
    f32x4 acc[2][6];
    #pragma unroll
    for (int a = 0; a < 2; ++a)
        #pragma unroll
        for (int j = 0; j < 6; ++j) acc[a][j] = (f32x4){0.f, 0.f, 0.f, 0.f};

    for (int ks = 0; ks < 16; ++ks) {
        int k0 = ks * 32;
        #pragma unroll
        for (int q = 0; q < 4; ++q) {
            int c = tid + q * 256;
            int s = c >> 9, r = (c >> 2) & 127, kc = c & 3;
            const unsigned short* src = (s ? hlo : hhi) + (long long)rid[r] * 512 + k0 + kc * 8;
            bf16x8 v = *(const bf16x8*)src;
            *(bf16x8*)&sA[s * 4096 + r * 32 + 8 * swz(r, kc)] = v;
        }
        __syncthreads();
        bf16x8 ahi[2], alo[2];
        #pragma unroll
        for (int a = 0; a < 2; ++a) {
            int r = w * 32 + a * 16 + (l & 15);
            int off = r * 32 + 8 * swz(r, l >> 4);
            ahi[a] = *(const bf16x8*)&sA[off];
            alo[a] = *(const bf16x8*)&sA[4096 + off];
        }
        #pragma unroll
        for (int j = 0; j < 6; ++j) {
            int fb = ((((ct * 16 + ks) * 6 + j) * 64) + l) * 8;
            bf16x8 bh = *(const bf16x8*)&wghi[fb];
            bf16x8 bl = *(const bf16x8*)&wglo[fb];
            #pragma unroll
            for (int a = 0; a < 2; ++a) {
                acc[a][j] = __builtin_amdgcn_mfma_f32_16x16x32_bf16(ahi[a], bh, acc[a][j], 0, 0, 0);
                acc[a][j] = __builtin_amdgcn_mfma_f32_16x16x32_bf16(alo[a], bh, acc[a][j], 0, 0, 0);
                acc[a][j] = __builtin_amdgcn_mfma_f32_16x16x32_bf16(ahi[a], bl, acc[a][j], 0, 0, 0);
            }
        }
        __syncthreads();
    }
    // gate tile through LDS (stride 97 to avoid bank conflicts)
    int q = l >> 4;
    #pragma unroll
    for (int a = 0; a < 2; ++a)
        #pragma unroll
        for (int j = 0; j < 6; ++j)
            #pragma unroll
            for (int r = 0; r < 4; ++r)
                gt[(w * 32 + a * 16 + q * 4 + r) * 97 + j * 16 + (l & 15)] = acc[a][j][r];
    __syncthreads();
    // epilogue: thread t -> row=t>>1, units (t&1)*8..+7 of this ct (16 units)
    int row = tid >> 1, ub = (tid & 1) * 8;
    int pos = rt * BM + row;
    if (pos < n) {
        int grow = rid[row];
        bf16x8 vh, vl;
        #pragma unroll
        for (int ui = 0; ui < 8; ++ui) {
            int u = ub + ui;
            const float* g = &gt[row * 97 + u * 6];
            int ug = ct * 16 + u;
            const float* c6 = &cgl[ug * 6];
            float ir = g[0] + c6[0], iz = g[1] + c6[1], in_ = g[2] + c6[2];
            float hr = g[3] + c6[3], hz = g[4] + c6[4], hn = g[5] + c6[5];
            float r = 1.f / (1.f + expf(-(ir + hr)));
            float z = 1.f / (1.f + expf(-(iz + hz)));
            float nn = tanhf(fmaf(r, hn, in_));
            long long off = (long long)grow * 512 + ug;
            float ho = bf2f(hhi[off]) + bf2f(hlo[off]);
            float hv = (1.f - z) * nn + z * ho;
            unsigned short hb = f2bf(hv);
            vh[ui] = (short)hb;
            vl[ui] = (short)f2bf(hv - bf2f(hb));
        }
        long long ob = (long long)grow * 512 + ct * 16 + ub;
        *(bf16x8*)&nhi[ob] = vh;
        *(bf16x8*)&nlo[ob] = vl;
    }
}

extern "C" void kernel_launch(void* const* d_in, const int* in_sizes, int n_in,
                              void* d_out, int out_size, void* d_ws, size_t ws_size,
                              hipStream_t stream) {
    const float* hidden  = (const float*)d_in[1];
    const float* halt_w1 = (const float*)d_in[2];
    const float* halt_b1 = (const float*)d_in[3];
    const float* halt_w2 = (const float*)d_in[4];
    const float* halt_b2 = (const float*)d_in[5];
    const float* w_ih    = (const float*)d_in[6];
    const float* w_hh    = (const float*)d_in[7];
    const float* b_ih    = (const float*)d_in[8];
    const float* b_hh    = (const float*)d_in[9];
    const float* demb    = (const float*)d_in[10];

    const int H = in_sizes[3];          // 512
    const int B = in_sizes[1] / H;      // 32768
    const int L = in_sizes[10] / H;     // 10

    float* out = (float*)d_out;

    char* wsp = (char*)d_ws;
    auto alloc = [&](size_t bytes) {
        char* p = wsp;
        wsp += (bytes + 255) & ~(size_t)255;
        return p;
    };
    unsigned short* hAhi = (unsigned short*)alloc((size_t)B * 512 * 2);
    unsigned short* hAlo = (unsigned short*)alloc((size_t)B * 512 * 2);
    unsigned short* hBhi = (unsigned short*)alloc((size_t)B * 512 * 2);
    unsigned short* hBlo = (unsigned short*)alloc((size_t)B * 512 * 2);
    unsigned short* w1fh = (unsigned short*)alloc((size_t)262144 * 2);
    unsigned short* w1fl = (unsigned short*)alloc((size_t)262144 * 2);
    unsigned short* wgfh = (unsigned short*)alloc((size_t)1572864 * 2);
    unsigned short* wgfl = (unsigned short*)alloc((size_t)1572864 * 2);
    float* cg    = (float*)alloc((size_t)L * 6 * 512 * 4);
    float* ppart = (float*)alloc((size_t)B * 4 * 4);
    float* cum   = (float*)alloc((size_t)B * 4);
    int* idxA    = (int*)alloc((size_t)B * 4);
    int* idxB    = (int*)alloc((size_t)B * 4);
    int* counts  = (int*)alloc(64);
    (void)ws_size; (void)n_in; (void)out_size;

    k_init<<<(B + 255) / 256, 256, 0, stream>>>(cum, idxA, counts, B);
    k_split<<<(B * 512 / 8 + 255) / 256, 256, 0, stream>>>(hidden, hAhi, hAlo, B * 512 / 8);
    k_prep_w1f<<<1024, 256, 0, stream>>>(halt_w1, w1fh, w1fl);
    k_prep_wgf<<<6144, 256, 0, stream>>>(w_ih, w_hh, wgfh, wgfl);
    k_prep_cg<<<120, 256, 0, stream>>>(demb, w_ih, b_ih, b_hh, cg, L);

    unsigned short* hch = hAhi; unsigned short* hcl = hAlo;
    unsigned short* hnh = hBhi; unsigned short* hnl = hBlo;
    int* ia = idxA;
    int* ib = idxB;

    dim3 hgrid((B + BM - 1) / BM, 4);
    dim3 ggrid((B + BM - 1) / BM, 32);

    for (int l = 0; l < L; ++l) {
        k_halt<<<hgrid, 256, 0, stream>>>(hch, hcl, ia, counts, l, w1fh, w1fl,
                                          halt_b1, halt_w2, ppart);
        k_book<<<8192, 256, 0, stream>>>(ppart, halt_b2, cum, hch, hcl, ia, counts, l,
                                         out, ib, counts + (l + 1), B, l == 0 ? 1 : 0);
        if (l + 1 < L) {
            k_gru<<<ggrid, 256, 0, stream>>>(hch, hcl, ib, counts, l + 1, wgfh, wgfl,
                                             cg + (size_t)l * 6 * 512, hnh, hnl);
            unsigned short* t;
            t = hch; hch = hnh; hnh = t;
            t = hcl; hcl = hnl; hnl = t;
            int* ti = ia; ia = ib; ib = ti;
        }
    }
}

// Round 8
// 1541.031 us; speedup vs baseline: 1.9798x; 1.1446x over previous
//
#include <hip/hip_runtime.h>

// ---------------------------------------------------------------------------
// ACT-GRU (B=32768, H=512, L=10), bf16x3 MFMA, BARRIER-FREE main loops.
// v3 changes vs v2:
//  - k_halt / k_gru main loops load A-fragments DIRECTLY from global per lane
//    (same gathered 16-row x 64B pattern the old LDS staging issued) -> no
//    LDS, no __syncthreads in the K loop; compiler pipelines loads over MFMAs.
//  - k_gru B-layout is gate-PLANAR: per 16-unit group, 6 fragments (one per
//    gate g: ihr,ihz,ihn,hhr,hhz,hhn). Lane (l&15) = unit -> all 6 gates of a
//    unit land in one lane's accumulators -> GRU nonlinearity fully
//    in-register. Epilogue uses a tiny 10KB LDS tile only to transpose
//    h_old/h_new for coalesced 16B IO.
// Numerics identical to v2 (same per-dot accumulation order): x = hi+lo bf16
// split, hi*hi + lo*hi + hi*lo on mfma_f32_16x16x32_bf16, fp32 accum.
// MFMA layouts (gfx950 16x16x32): A: row=l&15, k=(l>>4)*8+e ;
// B: col=l&15, k=(l>>4)*8+e ; C: col=l&15, row=(l>>4)*4+reg  [m89-verified].
// ---------------------------------------------------------------------------

typedef __attribute__((ext_vector_type(8))) short bf16x8;
typedef __attribute__((ext_vector_type(4))) float f32x4;

#define BM 128

__device__ __forceinline__ unsigned short f2bf(float x) {
    unsigned int u = __float_as_uint(x);
    u += 0x7fffu + ((u >> 16) & 1u);          // RTNE
    return (unsigned short)(u >> 16);
}
__device__ __forceinline__ float bf2f(unsigned short b) {
    return __uint_as_float(((unsigned int)b) << 16);
}

__global__ void k_init(float* __restrict__ cum, int* __restrict__ idxA,
                       int* __restrict__ counts, int B) {
    int i = blockIdx.x * blockDim.x + threadIdx.x;
    if (i < B) { cum[i] = 0.f; idxA[i] = i; }
    if (i == 0) { counts[0] = B; for (int l = 1; l < 16; ++l) counts[l] = 0; }
}

// split fp32 -> (hi,lo) bf16 pair, 8 elems/thread
__global__ void k_split(const float* __restrict__ x, unsigned short* __restrict__ hi,
                        unsigned short* __restrict__ lo, int n8) {
    int i = blockIdx.x * blockDim.x + threadIdx.x;
    if (i >= n8) return;
    const float4 v0 = ((const float4*)x)[2 * i];
    const float4 v1 = ((const float4*)x)[2 * i + 1];
    float v[8] = {v0.x, v0.y, v0.z, v0.w, v1.x, v1.y, v1.z, v1.w};
    bf16x8 vh, vl;
    #pragma unroll
    for (int e = 0; e < 8; ++e) {
        unsigned short h = f2bf(v[e]);
        vh[e] = (short)h;
        vl[e] = (short)f2bf(v[e] - bf2f(h));
    }
    *(bf16x8*)&hi[(long long)i * 8] = vh;
    *(bf16x8*)&lo[(long long)i * 8] = vl;
}

// halt W1 -> fragment-linear split: idx = ((((ct*16+ks)*8+j)*64+l)*8+e)
// col = ct*128+j*16+(l&15), k = ks*32+(l>>4)*8+e, val = w1[col*512+k]
__global__ void k_prep_w1f(const float* __restrict__ w1, unsigned short* __restrict__ fhi,
                           unsigned short* __restrict__ flo) {
    int i = blockIdx.x * blockDim.x + threadIdx.x;
    if (i >= 4 * 16 * 8 * 64 * 8) return;
    int e = i & 7, l = (i >> 3) & 63, j = (i >> 9) & 7, ks = (i >> 12) & 15, ct = i >> 16;
    int col = ct * 128 + j * 16 + (l & 15);
    int k = ks * 32 + (l >> 4) * 8 + e;
    float v = w1[(long long)col * 512 + k];
    unsigned short h = f2bf(v);
    fhi[i] = h;
    flo[i] = f2bf(v - bf2f(h));
}

// GRU gate weights, gate-PLANAR fragment-linear:
// idx = ((((ct*16+ks)*6+g)*64+l)*8+e); unit = ct*16+(l&15); k = ks*32+(l>>4)*8+e
// val: g<3 -> w_ih[(g*512+unit)*512+k] ; g>=3 -> w_hh[((g-3)*512+unit)*512+k]
__global__ void k_prep_wgf(const float* __restrict__ w_ih, const float* __restrict__ w_hh,
                           unsigned short* __restrict__ fhi, unsigned short* __restrict__ flo) {
    int i = blockIdx.x * blockDim.x + threadIdx.x;
    if (i >= 32 * 16 * 6 * 64 * 8) return;
    int e = i & 7, l = (i >> 3) & 63;
    int t = i >> 9;
    int g = t % 6;
    int ksct = t / 6;
    int ks = ksct & 15, ct = ksct >> 4;
    int unit = ct * 16 + (l & 15);
    int k = ks * 32 + (l >> 4) * 8 + e;
    float v = (g < 3) ? w_ih[((long long)(g * 512 + unit)) * 512 + k]
                      : w_hh[((long long)((g - 3) * 512 + unit)) * 512 + k];
    unsigned short h = f2bf(v);
    fhi[i] = h;
    flo[i] = f2bf(v - bf2f(h));
}

// cg[l][u*6+g] = (g<3) ? b_ih[g*512+u] + dot(emb[l], w_ih_row) : b_hh[(g-3)*512+u]
__global__ void k_prep_cg(const float* __restrict__ emb, const float* __restrict__ w_ih,
                          const float* __restrict__ b_ih, const float* __restrict__ b_hh,
                          float* __restrict__ cg, int L) {
    int total = L * 6 * 512;
    for (int i = blockIdx.x * blockDim.x + threadIdx.x; i < total;
         i += gridDim.x * blockDim.x) {
        int g = i % 6;
        int u = (i / 6) % 512;
        int l = i / (6 * 512);
        float v;
        if (g < 3) {
            const float* w = w_ih + (long long)(g * 512 + u) * 512;
            const float* e = emb + (long long)l * 512;
            float s = 0.f;
            #pragma unroll 8
            for (int k = 0; k < 512; ++k) s = fmaf(e[k], w[k], s);
            v = s + b_ih[g * 512 + u];
        } else {
            v = b_hh[(g - 3) * 512 + u];
        }
        cg[i] = v;
    }
}

// ---------------- halting GEMM (barrier-free, direct A gather) ----------------
__global__ __launch_bounds__(256, 3) void k_halt(
        const unsigned short* __restrict__ hhi, const unsigned short* __restrict__ hlo,
        const int* __restrict__ idx, const int* __restrict__ counts, int lslot,
        const unsigned short* __restrict__ w1hi, const unsigned short* __restrict__ w1lo,
        const float* __restrict__ b1, const float* __restrict__ w2,
        float* __restrict__ p_part) {
    int n = counts[lslot];
    int rt = blockIdx.x, ct = blockIdx.y;
    if (rt * BM >= n) return;
    int tid = threadIdx.x;
    int w = tid >> 6, l = tid & 63;
    int p0 = rt * BM + w * 32 + (l & 15);
    int r0 = idx[min(p0, n - 1)];
    int r1 = idx[min(p0 + 16, n - 1)];
    int ko = (l >> 4) * 8;
    const unsigned short* a0h = hhi + (long long)r0 * 512 + ko;
    const unsigned short* a0l = hlo + (long long)r0 * 512 + ko;
    const unsigned short* a1h = hhi + (long long)r1 * 512 + ko;
    const unsigned short* a1l = hlo + (long long)r1 * 512 + ko;
    // fragment elem index = ct*65536 + ks*4096 + j*512 + l*8
    const unsigned short* pbh = w1hi + (long long)ct * 65536 + l * 8;
    const unsigned short* pbl = w1lo + (long long)ct * 65536 + l * 8;

    f32x4 acc[2][8];
    #pragma unroll
    for (int a = 0; a < 2; ++a)
        #pragma unroll
        for (int j = 0; j < 8; ++j) acc[a][j] = (f32x4){0.f, 0.f, 0.f, 0.f};

    for (int ks = 0; ks < 16; ++ks) {
        bf16x8 va0h = *(const bf16x8*)(a0h + ks * 32);
        bf16x8 va0l = *(const bf16x8*)(a0l + ks * 32);
        bf16x8 va1h = *(const bf16x8*)(a1h + ks * 32);
        bf16x8 va1l = *(const bf16x8*)(a1l + ks * 32);
        #pragma unroll
        for (int j = 0; j < 8; ++j) {
            bf16x8 bh = *(const bf16x8*)(pbh + ks * 4096 + j * 512);
            bf16x8 bl = *(const bf16x8*)(pbl + ks * 4096 + j * 512);
            acc[0][j] = __builtin_amdgcn_mfma_f32_16x16x32_bf16(va0h, bh, acc[0][j], 0, 0, 0);
            acc[0][j] = __builtin_amdgcn_mfma_f32_16x16x32_bf16(va0l, bh, acc[0][j], 0, 0, 0);
            acc[0][j] = __builtin_amdgcn_mfma_f32_16x16x32_bf16(va0h, bl, acc[0][j], 0, 0, 0);
            acc[1][j] = __builtin_amdgcn_mfma_f32_16x16x32_bf16(va1h, bh, acc[1][j], 0, 0, 0);
            acc[1][j] = __builtin_amdgcn_mfma_f32_16x16x32_bf16(va1l, bh, acc[1][j], 0, 0, 0);
            acc[1][j] = __builtin_amdgcn_mfma_f32_16x16x32_bf16(va1h, bl, acc[1][j], 0, 0, 0);
        }
    }
    // epilogue: relu(acc + b1[c]) * w2[c], reduce over the 128 cols of this ct
    int q = l >> 4;
    float sums[2][4];
    #pragma unroll
    for (int a = 0; a < 2; ++a)
        #pragma unroll
        for (int r = 0; r < 4; ++r) sums[a][r] = 0.f;
    #pragma unroll
    for (int j = 0; j < 8; ++j) {
        int cb = ct * 128 + j * 16 + (l & 15);
        float bb = b1[cb], ww = w2[cb];
        #pragma unroll
        for (int a = 0; a < 2; ++a)
            #pragma unroll
            for (int r = 0; r < 4; ++r) {
                float v = acc[a][j][r] + bb;
                v = v > 0.f ? v : 0.f;
                sums[a][r] = fmaf(v, ww, sums[a][r]);
            }
    }
    #pragma unroll
    for (int m = 1; m < 16; m <<= 1)
        #pragma unroll
        for (int a = 0; a < 2; ++a)
            #pragma unroll
            for (int r = 0; r < 4; ++r) sums[a][r] += __shfl_xor(sums[a][r], m, 64);
    if ((l & 15) == 0) {
        #pragma unroll
        for (int a = 0; a < 2; ++a)
            #pragma unroll
            for (int r = 0; r < 4; ++r) {
                int pos = rt * BM + w * 32 + a * 16 + q * 4 + r;
                if (pos < n) p_part[(long long)pos * 4 + ct] = sums[a][r];
            }
    }
}

// ---------------- bookkeeping: one wave per row ----------------
__global__ void k_book(const float* __restrict__ p_part, const float* __restrict__ b2,
                       float* __restrict__ cum,
                       const unsigned short* __restrict__ hhi,
                       const unsigned short* __restrict__ hlo,
                       const int* __restrict__ idx, const int* __restrict__ counts, int lslot,
                       float* __restrict__ out, int* __restrict__ idx_next,
                       int* __restrict__ count_next, int B, int first) {
    int n = counts[lslot];
    int wv = (blockIdx.x * blockDim.x + threadIdx.x) >> 6;
    int lane = threadIdx.x & 63;
    int nw = (gridDim.x * blockDim.x) >> 6;
    for (int pos = wv; pos < n; pos += nw) {
        int row = idx[pos];
        float ps = 0.f;
        if (lane == 0) {
            float s = p_part[(long long)pos * 4 + 0] + p_part[(long long)pos * 4 + 1] +
                      p_part[(long long)pos * 4 + 2] + p_part[(long long)pos * 4 + 3] + b2[0];
            float p = 1.f / (1.f + expf(-s));
            float cb = cum[row];
            int halted = (p + cb > 0.9f);
            float rem = (1.f - cb) + 1e-15f;
            ps = halted ? rem : p;
            cum[row] = cb + ps;
            long long BH = (long long)B * 512;
            if (first) {
                out[BH + row]     = halted ? 0.f : ps;
                out[BH + B + row] = halted ? 0.f : 1.f;
            } else if (!halted) {
                out[BH + row]     += ps;
                out[BH + B + row] += 1.f;
            }
            if (!halted) idx_next[atomicAdd(count_next, 1)] = row;
        }
        ps = __shfl(ps, 0, 64);
        long long hb = (long long)row * 512 + lane * 8;
        bf16x8 vh = *(const bf16x8*)&hhi[hb];
        bf16x8 vl = *(const bf16x8*)&hlo[hb];
        float* mr = out + hb;
        float vals[8];
        #pragma unroll
        for (int e = 0; e < 8; ++e)
            vals[e] = bf2f((unsigned short)vh[e]) + bf2f((unsigned short)vl[e]);
        if (first) {
            #pragma unroll
            for (int e = 0; e < 8; ++e) mr[e] = vals[e] * ps;
        } else {
            #pragma unroll
            for (int e = 0; e < 8; ++e) mr[e] = fmaf(vals[e], ps, mr[e]);
        }
    }
}

// -------- GRU GEMM: barrier-free loop, gate-planar B, in-register epilogue --------
__global__ __launch_bounds__(256, 3) void k_gru(
        const unsigned short* __restrict__ hhi, const unsigned short* __restrict__ hlo,
        const int* __restrict__ idx, const int* __restrict__ counts, int lslot,
        const unsigned short* __restrict__ wghi, const unsigned short* __restrict__ wglo,
        const float* __restrict__ cgl,
        unsigned short* __restrict__ nhi, unsigned short* __restrict__ nlo) {
    int n = counts[lslot];
    int rt = blockIdx.x, ct = blockIdx.y;
    if (rt * BM >= n) return;
    __shared__ float hx[128 * 20];            // h_old/h_new transpose tile (10KB)
    int tid = threadIdx.x;
    int w = tid >> 6, l = tid & 63;
    int p0 = rt * BM + w * 32 + (l & 15);
    int r0 = idx[min(p0, n - 1)];
    int r1 = idx[min(p0 + 16, n - 1)];
    int ko = (l >> 4) * 8;
    const unsigned short* a0h = hhi + (long long)r0 * 512 + ko;
    const unsigned short* a0l = hlo + (long long)r0 * 512 + ko;
    const unsigned short* a1h = hhi + (long long)r1 * 512 + ko;
    const unsigned short* a1l = hlo + (long long)r1 * 512 + ko;
    // fragment elem index = ct*49152 + ks*3072 + g*512 + l*8
    const unsigned short* pbh = wghi + (long long)ct * 49152 + l * 8;
    const unsigned short* pbl = wglo + (long long)ct * 49152 + l * 8;
    int ug = ct * 16 + (l & 15);
    float cgv[6];
    #pragma unroll
    for (int g = 0; g < 6; ++g) cgv[g] = cgl[ug * 6 + g];

    f32x4 acc[2][6];
    #pragma unroll
    for (int a = 0; a < 2; ++a)
        #pragma unroll
        for (int g = 0; g < 6; ++g) acc[a][g] = (f32x4){0.f, 0.f, 0.f, 0.f};

    for (int ks = 0; ks < 16; ++ks) {
        bf16x8 va0h = *(const bf16x8*)(a0h + ks * 32);
        bf16x8 va0l = *(const bf16x8*)(a0l + ks * 32);
        bf16x8 va1h = *(const bf16x8*)(a1h + ks * 32);
        bf16x8 va1l = *(const bf16x8*)(a1l + ks * 32);
        #pragma unroll
        for (int g = 0; g < 6; ++g) {
            bf16x8 bh = *(const bf16x8*)(pbh + ks * 3072 + g * 512);
            bf16x8 bl = *(const bf16x8*)(pbl + ks * 3072 + g * 512);
            acc[0][g] = __builtin_amdgcn_mfma_f32_16x16x32_bf16(va0h, bh, acc[0][g], 0, 0, 0);
            acc[0][g] = __builtin_amdgcn_mfma_f32_16x16x32_bf16(va0l, bh, acc[0][g], 0, 0, 0);
            acc[0][g] = __builtin_amdgcn_mfma_f32_16x16x32_bf16(va0h, bl, acc[0][g], 0, 0, 0);
            acc[1][g] = __builtin_amdgcn_mfma_f32_16x16x32_bf16(va1h, bh, acc[1][g], 0, 0, 0);
            acc[1][g] = __builtin_amdgcn_mfma_f32_16x16x32_bf16(va1l, bh, acc[1][g], 0, 0, 0);
            acc[1][g] = __builtin_amdgcn_mfma_f32_16x16x32_bf16(va1h, bl, acc[1][g], 0, 0, 0);
        }
    }

    // ---- epilogue ----
    // phase 1: coalesced load of h_old tile (rows of this rt, 16 units of this ct)
    int erow = tid >> 1, eub = (tid & 1) * 8;
    int epos = rt * BM + erow;
    int egrow = idx[min(epos, n - 1)];
    long long hb = (long long)egrow * 512 + ct * 16 + eub;
    {
        bf16x8 oh = *(const bf16x8*)&hhi[hb];
        bf16x8 ol = *(const bf16x8*)&hlo[hb];
        #pragma unroll
        for (int e = 0; e < 8; ++e)
            hx[erow * 20 + eub + e] = bf2f((unsigned short)oh[e]) + bf2f((unsigned short)ol[e]);
    }
    __syncthreads();
    // phase 2: per-lane GRU nonlinearity (6 gates of unit ug, 8 rows per lane)
    #pragma unroll
    for (int a = 0; a < 2; ++a)
        #pragma unroll
        for (int r = 0; r < 4; ++r) {
            int row = w * 32 + a * 16 + (l >> 4) * 4 + r;
            float ho = hx[row * 20 + (l & 15)];
            float ir  = acc[a][0][r] + cgv[0];
            float iz  = acc[a][1][r] + cgv[1];
            float in_ = acc[a][2][r] + cgv[2];
            float hr  = acc[a][3][r] + cgv[3];
            float hz  = acc[a][4][r] + cgv[4];
            float hn  = acc[a][5][r] + cgv[5];
            float rr = 1.f / (1.f + expf(-(ir + hr)));
            float z  = 1.f / (1.f + expf(-(iz + hz)));
            float nn = tanhf(fmaf(rr, hn, in_));
            hx[row * 20 + (l & 15)] = (1.f - z) * nn + z * ho;   // same slot, same thread
        }
    __syncthreads();
    // phase 3: coalesced split + store of h_new
    if (epos < n) {
        bf16x8 vh, vl;
        #pragma unroll
        for (int e = 0; e < 8; ++e) {
            float v = hx[erow * 20 + eub + e];
            unsigned short hbv = f2bf(v);
            vh[e] = (short)hbv;
            vl[e] = (short)f2bf(v - bf2f(hbv));
        }
        *(bf16x8*)&nhi[hb] = vh;
        *(bf16x8*)&nlo[hb] = vl;
    }
}

extern "C" void kernel_launch(void* const* d_in, const int* in_sizes, int n_in,
                              void* d_out, int out_size, void* d_ws, size_t ws_size,
                              hipStream_t stream) {
    const float* hidden  = (const float*)d_in[1];
    const float* halt_w1 = (const float*)d_in[2];
    const float* halt_b1 = (const float*)d_in[3];
    const float* halt_w2 = (const float*)d_in[4];
    const float* halt_b2 = (const float*)d_in[5];
    const float* w_ih    = (const float*)d_in[6];
    const float* w_hh    = (const float*)d_in[7];
    const float* b_ih    = (const float*)d_in[8];
    const float* b_hh    = (const float*)d_in[9];
    const float* demb    = (const float*)d_in[10];

    const int H = in_sizes[3];          // 512
    const int B = in_sizes[1] / H;      // 32768
    const int L = in_sizes[10] / H;     // 10

    float* out = (float*)d_out;

    char* wsp = (char*)d_ws;
    auto alloc = [&](size_t bytes) {
        char* p = wsp;
        wsp += (bytes + 255) & ~(size_t)255;
        return p;
    };
    unsigned short* hAhi = (unsigned short*)alloc((size_t)B * 512 * 2);
    unsigned short* hAlo = (unsigned short*)alloc((size_t)B * 512 * 2);
    unsigned short* hBhi = (unsigned short*)alloc((size_t)B * 512 * 2);
    unsigned short* hBlo = (unsigned short*)alloc((size_t)B * 512 * 2);
    unsigned short* w1fh = (unsigned short*)alloc((size_t)262144 * 2);
    unsigned short* w1fl = (unsigned short*)alloc((size_t)262144 * 2);
    unsigned short* wgfh = (unsigned short*)alloc((size_t)1572864 * 2);
    unsigned short* wgfl = (unsigned short*)alloc((size_t)1572864 * 2);
    float* cg    = (float*)alloc((size_t)L * 6 * 512 * 4);
    float* ppart = (float*)alloc((size_t)B * 4 * 4);
    float* cum   = (float*)alloc((size_t)B * 4);
    int* idxA    = (int*)alloc((size_t)B * 4);
    int* idxB    = (int*)alloc((size_t)B * 4);
    int* counts  = (int*)alloc(64);
    (void)ws_size; (void)n_in; (void)out_size;

    k_init<<<(B + 255) / 256, 256, 0, stream>>>(cum, idxA, counts, B);
    k_split<<<(B * 512 / 8 + 255) / 256, 256, 0, stream>>>(hidden, hAhi, hAlo, B * 512 / 8);
    k_prep_w1f<<<1024, 256, 0, stream>>>(halt_w1, w1fh, w1fl);
    k_prep_wgf<<<6144, 256, 0, stream>>>(w_ih, w_hh, wgfh, wgfl);
    k_prep_cg<<<120, 256, 0, stream>>>(demb, w_ih, b_ih, b_hh, cg, L);

    unsigned short* hch = hAhi; unsigned short* hcl = hAlo;
    unsigned short* hnh = hBhi; unsigned short* hnl = hBlo;
    int* ia = idxA;
    int* ib = idxB;

    dim3 hgrid((B + BM - 1) / BM, 4);
    dim3 ggrid((B + BM - 1) / BM, 32);

    for (int l = 0; l < L; ++l) {
        k_halt<<<hgrid, 256, 0, stream>>>(hch, hcl, ia, counts, l, w1fh, w1fl,
                                          halt_b1, halt_w2, ppart);
        k_book<<<8192, 256, 0, stream>>>(ppart, halt_b2, cum, hch, hcl, ia, counts, l,
                                         out, ib, counts + (l + 1), B, l == 0 ? 1 : 0);
        if (l + 1 < L) {
            k_gru<<<ggrid, 256, 0, stream>>>(hch, hcl, ib, counts, l + 1, wgfh, wgfl,
                                             cg + (size_t)l * 6 * 512, hnh, hnl);
            unsigned short* t;
            t = hch; hch = hnh; hnh = t;
            t = hcl; hcl = hnl; hnl = t;
            int* ti = ia; ia = ib; ib = ti;
        }
    }
}